// Round 1
// baseline (419.623 us; speedup 1.0000x reference)
//
#include <hip/hip_runtime.h>
#include <math.h>

#define THREADS 256

// ---------------- degree counting ----------------
__global__ void k_deg(const int* __restrict__ src, const int* __restrict__ dst,
                      int* __restrict__ deg_s, int* __restrict__ deg_d, int E) {
    int e = blockIdx.x * blockDim.x + threadIdx.x;
    if (e < E) {
        atomicAdd(&deg_s[src[e]], 1);
        atomicAdd(&deg_d[dst[e]], 1);
    }
}

// ---------------- norms: deg^{-1/2}, 0 for deg==0 ----------------
__global__ void k_norm(const int* __restrict__ deg_s, const int* __restrict__ deg_d,
                       float* __restrict__ ns, float* __restrict__ nd, int N) {
    int i = blockIdx.x * blockDim.x + threadIdx.x;
    if (i < N) {
        int a = deg_s[i], b = deg_d[i];
        ns[i] = (a > 0) ? 1.0f / sqrtf((float)a) : 0.0f;
        nd[i] = (b > 0) ? 1.0f / sqrtf((float)b) : 0.0f;
    }
}

// ---------------- 3-kernel exclusive scan of deg_dst -> row_ptr ----------------
__global__ void k_scan1(const int* __restrict__ deg, int* __restrict__ excl,
                        int* __restrict__ bsum, int N) {
    __shared__ int s[THREADS];
    int t = threadIdx.x;
    int i = blockIdx.x * THREADS + t;
    int v = (i < N) ? deg[i] : 0;
    s[t] = v;
    __syncthreads();
    for (int off = 1; off < THREADS; off <<= 1) {
        int x = (t >= off) ? s[t - off] : 0;
        __syncthreads();
        s[t] += x;
        __syncthreads();
    }
    if (i < N) excl[i] = s[t] - v;
    if (t == THREADS - 1) bsum[blockIdx.x] = s[t];
}

__global__ void k_scan2(int* __restrict__ bsum, int nb) {
    __shared__ int s[THREADS];
    int t = threadIdx.x;
    int v = (t < nb) ? bsum[t] : 0;
    s[t] = v;
    __syncthreads();
    for (int off = 1; off < THREADS; off <<= 1) {
        int x = (t >= off) ? s[t - off] : 0;
        __syncthreads();
        s[t] += x;
        __syncthreads();
    }
    if (t < nb) bsum[t] = s[t] - v;  // exclusive block offsets
}

__global__ void k_scan3(int* __restrict__ rp, int* __restrict__ cur,
                        const int* __restrict__ bsum, int N) {
    int i = blockIdx.x * blockDim.x + threadIdx.x;
    if (i < N) {
        int v = rp[i] + bsum[i / THREADS];
        rp[i] = v;
        cur[i] = v;
    }
}

// ---------------- CSR fill (counting sort by dst) ----------------
__global__ void k_fill(const int* __restrict__ src, const int* __restrict__ dst,
                       int* __restrict__ cur, int* __restrict__ col, int E) {
    int e = blockIdx.x * blockDim.x + threadIdx.x;
    if (e < E) {
        int p = atomicAdd(&cur[dst[e]], 1);
        col[p] = src[e];
    }
}

// ---------------- H = (X * norm_src) @ W   (64x64 tile, 4x4 per thread) -------
// LDS: Xs stride 68 (16B-aligned rows, breaks 4-row-group bank aliasing)
#define XS_STRIDE 68
__global__ __launch_bounds__(256)
void k_gemm64(const float* __restrict__ X, const float* __restrict__ norm,
              const float* __restrict__ W, float* __restrict__ H, int N) {
    __shared__ float Xs[64 * XS_STRIDE];
    __shared__ float Ws[64 * 64];
    int tid = threadIdx.x;
    int rowBase = blockIdx.x * 64;

    // stage W (64x64), coalesced
    for (int i = tid; i < 4096; i += 256) Ws[i] = W[i];
    // stage X tile with norm_src row scaling, float4 coalesced
    for (int i = tid; i < 1024; i += 256) {
        int r  = i >> 4;        // 0..63
        int k4 = i & 15;        // float4 index within row
        int row = rowBase + r;
        float4 v = make_float4(0.f, 0.f, 0.f, 0.f);
        if (row < N) {
            v = ((const float4*)X)[(size_t)row * 16 + k4];
            float nv = norm[row];
            v.x *= nv; v.y *= nv; v.z *= nv; v.w *= nv;
        }
        *((float4*)&Xs[r * XS_STRIDE + (k4 << 2)]) = v;
    }
    __syncthreads();

    int tc = tid & 15;   // col group (cols tc*4 .. tc*4+3)
    int tr = tid >> 4;   // row group (rows tr*4 .. tr*4+3)
    int c0 = tc * 4, r0 = tr * 4;
    float acc[4][4] = {};

#pragma unroll
    for (int k = 0; k < 64; k += 4) {
        float4 xv[4];
#pragma unroll
        for (int j = 0; j < 4; j++)
            xv[j] = *((const float4*)&Xs[(r0 + j) * XS_STRIDE + k]);
#pragma unroll
        for (int kk = 0; kk < 4; kk++) {
            float4 wv = *((const float4*)&Ws[(k + kk) * 64 + c0]);
#pragma unroll
            for (int j = 0; j < 4; j++) {
                float xj = (kk == 0) ? xv[j].x : (kk == 1) ? xv[j].y
                         : (kk == 2) ? xv[j].z : xv[j].w;
                acc[j][0] += xj * wv.x;
                acc[j][1] += xj * wv.y;
                acc[j][2] += xj * wv.z;
                acc[j][3] += xj * wv.w;
            }
        }
    }
#pragma unroll
    for (int j = 0; j < 4; j++) {
        int row = rowBase + r0 + j;
        if (row < N) {
            float4 o = make_float4(acc[j][0], acc[j][1], acc[j][2], acc[j][3]);
            *((float4*)&H[(size_t)row * 64 + c0]) = o;
        }
    }
}

// ------- Out[i,c] = tanh( norm_dst[i] * sum_{e in CSR row i} H[col[e], c] + b[c] )
// one wave per node; lane = channel; 256B coalesced gather per edge
__global__ __launch_bounds__(256)
void k_agg(const float* __restrict__ H, const int* __restrict__ rp,
           const int* __restrict__ deg, const int* __restrict__ col,
           const float* __restrict__ nd, const float* __restrict__ bias,
           float* __restrict__ Out, int N) {
    int wave = threadIdx.x >> 6;
    int c = threadIdx.x & 63;
    int node = blockIdx.x * 4 + wave;
    if (node >= N) return;
    int start = rp[node];
    int n = deg[node];
    float acc = 0.0f;
    int j = 0;
    for (; j + 4 <= n; j += 4) {
        int s0 = col[start + j + 0];
        int s1 = col[start + j + 1];
        int s2 = col[start + j + 2];
        int s3 = col[start + j + 3];
        float a0 = H[(size_t)s0 * 64 + c];
        float a1 = H[(size_t)s1 * 64 + c];
        float a2 = H[(size_t)s2 * 64 + c];
        float a3 = H[(size_t)s3 * 64 + c];
        acc += a0 + a1 + a2 + a3;
    }
    for (; j < n; j++)
        acc += H[(size_t)col[start + j] * 64 + c];
    float v = acc * nd[node] + bias[c];
    Out[(size_t)node * 64 + c] = tanhf(v);
}

// ---------------- final FC: out = X @ Wfc + bfc  (64x10) ----------------
__global__ __launch_bounds__(640)
void k_fc(const float* __restrict__ X, const float* __restrict__ W,
          const float* __restrict__ b, float* __restrict__ out, int N) {
    __shared__ float Ws[640];
    __shared__ float bs[10];
    __shared__ float Xs[64 * 65];
    int tid = threadIdx.x;
    Ws[tid] = W[tid];
    if (tid < 10) bs[tid] = b[tid];
    int nodeBase = blockIdx.x * 64;
    for (int i = tid; i < 4096; i += 640) {
        int r = i >> 6, cc = i & 63;
        int nn = nodeBase + r;
        Xs[r * 65 + cc] = (nn < N) ? X[(size_t)nn * 64 + cc] : 0.0f;
    }
    __syncthreads();
    int ln = tid / 10, cl = tid % 10;
    float acc = bs[cl];
#pragma unroll
    for (int k = 0; k < 64; k++)
        acc += Xs[ln * 65 + k] * Ws[k * 10 + cl];
    int node = nodeBase + ln;
    if (node < N) out[(size_t)node * 10 + cl] = acc;
}

extern "C" void kernel_launch(void* const* d_in, const int* in_sizes, int n_in,
                              void* d_out, int out_size, void* d_ws, size_t ws_size,
                              hipStream_t stream) {
    const float* x   = (const float*)d_in[0];
    const int*   src = (const int*)d_in[1];
    const int*   dst = (const int*)d_in[2];
    const float* W1  = (const float*)d_in[3];
    const float* b1  = (const float*)d_in[4];
    const float* W2  = (const float*)d_in[5];
    const float* b2  = (const float*)d_in[6];
    const float* W3  = (const float*)d_in[7];
    const float* b3  = (const float*)d_in[8];
    const float* Wfc = (const float*)d_in[9];
    const float* bfc = (const float*)d_in[10];
    float* out = (float*)d_out;
    int N = in_sizes[0] / 64;
    int E = in_sizes[1];

    // workspace carve-out (256B aligned chunks)
    char* ws = (char*)d_ws;
    size_t p = 0;
    auto alloc = [&](size_t bytes) -> void* {
        void* r = ws + p;
        p = (p + bytes + 255) & ~(size_t)255;
        return r;
    };
    int*   deg_s = (int*)alloc((size_t)N * 4);
    int*   deg_d = (int*)alloc((size_t)N * 4);
    int*   rp    = (int*)alloc((size_t)N * 4);
    int*   cur   = (int*)alloc((size_t)N * 4);
    int*   bsum  = (int*)alloc((size_t)THREADS * 4);
    int*   col   = (int*)alloc((size_t)E * 4);
    float* ns    = (float*)alloc((size_t)N * 4);
    float* nd    = (float*)alloc((size_t)N * 4);
    float* bufH  = (float*)alloc((size_t)N * 64 * 4);
    float* bufX  = (float*)alloc((size_t)N * 64 * 4);
    (void)ws_size; (void)n_in; (void)out_size;

    hipMemsetAsync(deg_s, 0, (size_t)N * 4, stream);
    hipMemsetAsync(deg_d, 0, (size_t)N * 4, stream);

    int gE = (E + THREADS - 1) / THREADS;
    int gN = (N + THREADS - 1) / THREADS;

    k_deg  <<<gE, THREADS, 0, stream>>>(src, dst, deg_s, deg_d, E);
    k_norm <<<gN, THREADS, 0, stream>>>(deg_s, deg_d, ns, nd, N);
    k_scan1<<<gN, THREADS, 0, stream>>>(deg_d, rp, bsum, N);
    k_scan2<<<1,  THREADS, 0, stream>>>(bsum, gN);
    k_scan3<<<gN, THREADS, 0, stream>>>(rp, cur, bsum, N);
    k_fill <<<gE, THREADS, 0, stream>>>(src, dst, cur, col, E);

    int gG = (N + 63) / 64;   // gemm: 64-row tiles
    int gA = (N + 3) / 4;     // agg: 4 nodes (waves) per block
    int gF = (N + 63) / 64;   // fc: 64-node tiles

    // layer 1
    k_gemm64<<<gG, 256, 0, stream>>>(x,    ns, W1, bufH, N);
    k_agg   <<<gA, 256, 0, stream>>>(bufH, rp, deg_d, col, nd, b1, bufX, N);
    // layer 2
    k_gemm64<<<gG, 256, 0, stream>>>(bufX, ns, W2, bufH, N);
    k_agg   <<<gA, 256, 0, stream>>>(bufH, rp, deg_d, col, nd, b2, bufX, N);
    // layer 3
    k_gemm64<<<gG, 256, 0, stream>>>(bufX, ns, W3, bufH, N);
    k_agg   <<<gA, 256, 0, stream>>>(bufH, rp, deg_d, col, nd, b3, bufX, N);
    // FC head
    k_fc    <<<gF, 640, 0, stream>>>(bufX, Wfc, bfc, out, N);
}

// Round 2
// 400.210 us; speedup vs baseline: 1.0485x; 1.0485x over previous
//
#include <hip/hip_runtime.h>
#include <math.h>

#define THREADS 256

// ---------------- degree counting ----------------
__global__ void k_deg(const int* __restrict__ src, const int* __restrict__ dst,
                      int* __restrict__ deg_s, int* __restrict__ deg_d, int E) {
    int e = blockIdx.x * blockDim.x + threadIdx.x;
    if (e < E) {
        atomicAdd(&deg_s[src[e]], 1);
        atomicAdd(&deg_d[dst[e]], 1);
    }
}

// ---------------- 3-kernel exclusive scan of deg_dst -> row_ptr ----------------
__global__ void k_scan1(const int* __restrict__ deg, int* __restrict__ excl,
                        int* __restrict__ bsum, int N) {
    __shared__ int s[THREADS];
    int t = threadIdx.x;
    int i = blockIdx.x * THREADS + t;
    int v = (i < N) ? deg[i] : 0;
    s[t] = v;
    __syncthreads();
    for (int off = 1; off < THREADS; off <<= 1) {
        int x = (t >= off) ? s[t - off] : 0;
        __syncthreads();
        s[t] += x;
        __syncthreads();
    }
    if (i < N) excl[i] = s[t] - v;
    if (t == THREADS - 1) bsum[blockIdx.x] = s[t];
}

__global__ void k_scan2(int* __restrict__ bsum, int nb) {
    __shared__ int s[THREADS];
    int t = threadIdx.x;
    int v = (t < nb) ? bsum[t] : 0;
    s[t] = v;
    __syncthreads();
    for (int off = 1; off < THREADS; off <<= 1) {
        int x = (t >= off) ? s[t - off] : 0;
        __syncthreads();
        s[t] += x;
        __syncthreads();
    }
    if (t < nb) bsum[t] = s[t] - v;  // exclusive block offsets
}

// scan finalize + norms fused
__global__ void k_scan3(int* __restrict__ rp, int* __restrict__ cur,
                        const int* __restrict__ bsum,
                        const int* __restrict__ deg_s, const int* __restrict__ deg_d,
                        float* __restrict__ ns, float* __restrict__ nd, int N) {
    int i = blockIdx.x * blockDim.x + threadIdx.x;
    if (i < N) {
        int v = rp[i] + bsum[i / THREADS];
        rp[i] = v;
        cur[i] = v;
        int a = deg_s[i], b = deg_d[i];
        ns[i] = (a > 0) ? 1.0f / sqrtf((float)a) : 0.0f;
        nd[i] = (b > 0) ? 1.0f / sqrtf((float)b) : 0.0f;
    }
}

// ---------------- CSR fill (counting sort by dst) ----------------
__global__ void k_fill(const int* __restrict__ src, const int* __restrict__ dst,
                       int* __restrict__ cur, int* __restrict__ col, int E) {
    int e = blockIdx.x * blockDim.x + threadIdx.x;
    if (e < E) {
        int p = atomicAdd(&cur[dst[e]], 1);
        col[p] = src[e];
    }
}

// ---------------- H = (X * norm_src) @ W   (64x64 tile, 4x4 per thread) -------
#define XS_STRIDE 68
__global__ __launch_bounds__(256)
void k_gemm64(const float* __restrict__ X, const float* __restrict__ norm,
              const float* __restrict__ W, float* __restrict__ H, int N) {
    __shared__ float Xs[64 * XS_STRIDE];
    __shared__ float Ws[64 * 64];
    int tid = threadIdx.x;
    int rowBase = blockIdx.x * 64;

    for (int i = tid; i < 4096; i += 256) Ws[i] = W[i];
    for (int i = tid; i < 1024; i += 256) {
        int r  = i >> 4;
        int k4 = i & 15;
        int row = rowBase + r;
        float4 v = make_float4(0.f, 0.f, 0.f, 0.f);
        if (row < N) {
            v = ((const float4*)X)[(size_t)row * 16 + k4];
            float nv = norm[row];
            v.x *= nv; v.y *= nv; v.z *= nv; v.w *= nv;
        }
        *((float4*)&Xs[r * XS_STRIDE + (k4 << 2)]) = v;
    }
    __syncthreads();

    int tc = tid & 15;
    int tr = tid >> 4;
    int c0 = tc * 4, r0 = tr * 4;
    float acc[4][4] = {};

#pragma unroll
    for (int k = 0; k < 64; k += 4) {
        float4 xv[4];
#pragma unroll
        for (int j = 0; j < 4; j++)
            xv[j] = *((const float4*)&Xs[(r0 + j) * XS_STRIDE + k]);
#pragma unroll
        for (int kk = 0; kk < 4; kk++) {
            float4 wv = *((const float4*)&Ws[(k + kk) * 64 + c0]);
#pragma unroll
            for (int j = 0; j < 4; j++) {
                float xj = (kk == 0) ? xv[j].x : (kk == 1) ? xv[j].y
                         : (kk == 2) ? xv[j].z : xv[j].w;
                acc[j][0] += xj * wv.x;
                acc[j][1] += xj * wv.y;
                acc[j][2] += xj * wv.z;
                acc[j][3] += xj * wv.w;
            }
        }
    }
#pragma unroll
    for (int j = 0; j < 4; j++) {
        int row = rowBase + r0 + j;
        if (row < N) {
            float4 o = make_float4(acc[j][0], acc[j][1], acc[j][2], acc[j][3]);
            *((float4*)&H[(size_t)row * 64 + c0]) = o;
        }
    }
}

// ------- Out[i,:] = tanh( norm_dst[i] * sum_{e in row i} H[col[e], :] + b )
// one wave per node. 64 edge indices preloaded per wave (one coalesced load),
// distributed via shfl. float4 gathers: lane group g (of 4) loads edge j+g,
// 16 lanes/group * 16B = 256B per group, 4 edges per vmem instruction.
__global__ __launch_bounds__(256)
void k_agg(const float4* __restrict__ H4, const int* __restrict__ rp,
           const int* __restrict__ deg, const int* __restrict__ col,
           const float* __restrict__ nd, const float4* __restrict__ bias4,
           float4* __restrict__ Out4, int N) {
    int wave = threadIdx.x >> 6;
    int lane = threadIdx.x & 63;
    int node = blockIdx.x * 4 + wave;
    if (node >= N) return;
    int start = rp[node];
    int n = deg[node];
    int g = lane >> 4;   // edge subgroup 0..3
    int l = lane & 15;   // float4 index within row
    float ax = 0.f, ay = 0.f, az = 0.f, aw = 0.f;

    for (int base = 0; base < n; base += 64) {
        int cnt = n - base;
        if (cnt > 64) cnt = 64;
        int idx = (lane < cnt) ? col[start + base + lane] : 0;
        int j = 0;
        for (; j + 8 <= cnt; j += 8) {
            int s0 = __shfl(idx, j + g);
            int s1 = __shfl(idx, j + 4 + g);
            float4 v0 = H4[(size_t)s0 * 16 + l];
            float4 v1 = H4[(size_t)s1 * 16 + l];
            ax += v0.x + v1.x;
            ay += v0.y + v1.y;
            az += v0.z + v1.z;
            aw += v0.w + v1.w;
        }
        for (; j + 4 <= cnt; j += 4) {
            int s0 = __shfl(idx, j + g);
            float4 v0 = H4[(size_t)s0 * 16 + l];
            ax += v0.x; ay += v0.y; az += v0.z; aw += v0.w;
        }
        int t = cnt - j;
        if (t > 0) {
            int s0 = __shfl(idx, j + (g < t ? g : 0));
            if (g < t) {
                float4 v0 = H4[(size_t)s0 * 16 + l];
                ax += v0.x; ay += v0.y; az += v0.z; aw += v0.w;
            }
        }
    }
    // fold the 4 edge subgroups (xor 16, 32)
    ax += __shfl_xor(ax, 16); ay += __shfl_xor(ay, 16);
    az += __shfl_xor(az, 16); aw += __shfl_xor(aw, 16);
    ax += __shfl_xor(ax, 32); ay += __shfl_xor(ay, 32);
    az += __shfl_xor(az, 32); aw += __shfl_xor(aw, 32);

    if (lane < 16) {
        float nv = nd[node];
        float4 b = bias4[l];
        float4 r;
        r.x = tanhf(ax * nv + b.x);
        r.y = tanhf(ay * nv + b.y);
        r.z = tanhf(az * nv + b.z);
        r.w = tanhf(aw * nv + b.w);
        Out4[(size_t)node * 16 + l] = r;
    }
}

// ---------------- final FC: out = X @ Wfc + bfc  (64x10) ----------------
__global__ __launch_bounds__(640)
void k_fc(const float* __restrict__ X, const float* __restrict__ W,
          const float* __restrict__ b, float* __restrict__ out, int N) {
    __shared__ float Ws[640];
    __shared__ float bs[10];
    __shared__ float Xs[64 * 65];
    int tid = threadIdx.x;
    Ws[tid] = W[tid];
    if (tid < 10) bs[tid] = b[tid];
    int nodeBase = blockIdx.x * 64;
    for (int i = tid; i < 4096; i += 640) {
        int r = i >> 6, cc = i & 63;
        int nn = nodeBase + r;
        Xs[r * 65 + cc] = (nn < N) ? X[(size_t)nn * 64 + cc] : 0.0f;
    }
    __syncthreads();
    int ln = tid / 10, cl = tid % 10;
    float acc = bs[cl];
#pragma unroll
    for (int k = 0; k < 64; k++)
        acc += Xs[ln * 65 + k] * Ws[k * 10 + cl];
    int node = nodeBase + ln;
    if (node < N) out[(size_t)node * 10 + cl] = acc;
}

extern "C" void kernel_launch(void* const* d_in, const int* in_sizes, int n_in,
                              void* d_out, int out_size, void* d_ws, size_t ws_size,
                              hipStream_t stream) {
    const float* x   = (const float*)d_in[0];
    const int*   src = (const int*)d_in[1];
    const int*   dst = (const int*)d_in[2];
    const float* W1  = (const float*)d_in[3];
    const float* b1  = (const float*)d_in[4];
    const float* W2  = (const float*)d_in[5];
    const float* b2  = (const float*)d_in[6];
    const float* W3  = (const float*)d_in[7];
    const float* b3  = (const float*)d_in[8];
    const float* Wfc = (const float*)d_in[9];
    const float* bfc = (const float*)d_in[10];
    float* out = (float*)d_out;
    int N = in_sizes[0] / 64;
    int E = in_sizes[1];

    char* ws = (char*)d_ws;
    size_t p = 0;
    auto alloc = [&](size_t bytes) -> void* {
        void* r = ws + p;
        p = (p + bytes + 255) & ~(size_t)255;
        return r;
    };
    int*   deg_s = (int*)alloc((size_t)N * 4);
    int*   deg_d = (int*)alloc((size_t)N * 4);
    int*   rp    = (int*)alloc((size_t)N * 4);
    int*   cur   = (int*)alloc((size_t)N * 4);
    int*   bsum  = (int*)alloc((size_t)THREADS * 4);
    int*   col   = (int*)alloc((size_t)E * 4);
    float* ns    = (float*)alloc((size_t)N * 4);
    float* nd    = (float*)alloc((size_t)N * 4);
    float* bufH  = (float*)alloc((size_t)N * 64 * 4);
    float* bufX  = (float*)alloc((size_t)N * 64 * 4);
    (void)ws_size; (void)n_in; (void)out_size;

    hipMemsetAsync(deg_s, 0, (size_t)N * 4, stream);
    hipMemsetAsync(deg_d, 0, (size_t)N * 4, stream);

    int gE = (E + THREADS - 1) / THREADS;
    int gN = (N + THREADS - 1) / THREADS;

    k_deg  <<<gE, THREADS, 0, stream>>>(src, dst, deg_s, deg_d, E);
    k_scan1<<<gN, THREADS, 0, stream>>>(deg_d, rp, bsum, N);
    k_scan2<<<1,  THREADS, 0, stream>>>(bsum, gN);
    k_scan3<<<gN, THREADS, 0, stream>>>(rp, cur, bsum, deg_s, deg_d, ns, nd, N);
    k_fill <<<gE, THREADS, 0, stream>>>(src, dst, cur, col, E);

    int gG = (N + 63) / 64;
    int gA = (N + 3) / 4;
    int gF = (N + 63) / 64;

    k_gemm64<<<gG, 256, 0, stream>>>(x,    ns, W1, bufH, N);
    k_agg   <<<gA, 256, 0, stream>>>((const float4*)bufH, rp, deg_d, col, nd,
                                     (const float4*)b1, (float4*)bufX, N);
    k_gemm64<<<gG, 256, 0, stream>>>(bufX, ns, W2, bufH, N);
    k_agg   <<<gA, 256, 0, stream>>>((const float4*)bufH, rp, deg_d, col, nd,
                                     (const float4*)b2, (float4*)bufX, N);
    k_gemm64<<<gG, 256, 0, stream>>>(bufX, ns, W3, bufH, N);
    k_agg   <<<gA, 256, 0, stream>>>((const float4*)bufH, rp, deg_d, col, nd,
                                     (const float4*)b3, (float4*)bufX, N);
    k_fc    <<<gF, 640, 0, stream>>>(bufX, Wfc, bfc, out, N);
}

// Round 3
// 347.222 us; speedup vs baseline: 1.2085x; 1.1526x over previous
//
#include <hip/hip_runtime.h>
#include <hip/hip_fp16.h>
#include <math.h>

#define THREADS 256

// ---------------- degree counting + dst-rank capture ----------------
__global__ void k_deg(const int* __restrict__ src, const int* __restrict__ dst,
                      int* __restrict__ deg_s, int* __restrict__ deg_d,
                      int* __restrict__ rank, int E) {
    int e = blockIdx.x * blockDim.x + threadIdx.x;
    if (e < E) {
        atomicAdd(&deg_s[src[e]], 1);
        int p = atomicAdd(&deg_d[dst[e]], 1);
        rank[e] = p;   // within-dst ordinal; makes k_fill atomic-free
    }
}

// ---------------- 3-kernel exclusive scan of deg_dst -> row_ptr ----------------
__global__ void k_scan1(const int* __restrict__ deg, int* __restrict__ excl,
                        int* __restrict__ bsum, int N) {
    __shared__ int s[THREADS];
    int t = threadIdx.x;
    int i = blockIdx.x * THREADS + t;
    int v = (i < N) ? deg[i] : 0;
    s[t] = v;
    __syncthreads();
    for (int off = 1; off < THREADS; off <<= 1) {
        int x = (t >= off) ? s[t - off] : 0;
        __syncthreads();
        s[t] += x;
        __syncthreads();
    }
    if (i < N) excl[i] = s[t] - v;
    if (t == THREADS - 1) bsum[blockIdx.x] = s[t];
}

__global__ void k_scan2(int* __restrict__ bsum, int nb) {
    __shared__ int s[THREADS];
    int t = threadIdx.x;
    int v = (t < nb) ? bsum[t] : 0;
    s[t] = v;
    __syncthreads();
    for (int off = 1; off < THREADS; off <<= 1) {
        int x = (t >= off) ? s[t - off] : 0;
        __syncthreads();
        s[t] += x;
        __syncthreads();
    }
    if (t < nb) bsum[t] = s[t] - v;  // exclusive block offsets
}

// scan finalize + norms fused
__global__ void k_scan3(int* __restrict__ rp, const int* __restrict__ bsum,
                        const int* __restrict__ deg_s, const int* __restrict__ deg_d,
                        float* __restrict__ ns, float* __restrict__ nd, int N) {
    int i = blockIdx.x * blockDim.x + threadIdx.x;
    if (i < N) {
        rp[i] += bsum[i / THREADS];
        int a = deg_s[i], b = deg_d[i];
        ns[i] = (a > 0) ? 1.0f / sqrtf((float)a) : 0.0f;
        nd[i] = (b > 0) ? 1.0f / sqrtf((float)b) : 0.0f;
    }
}

// ---------------- CSR fill, atomic-free (uses rank) ----------------
__global__ void k_fill(const int* __restrict__ src, const int* __restrict__ dst,
                       const int* __restrict__ rp, const int* __restrict__ rank,
                       int* __restrict__ col, int E) {
    int e = blockIdx.x * blockDim.x + threadIdx.x;
    if (e < E) {
        int d = dst[e];
        col[rp[d] + rank[e]] = src[e];
    }
}

// ---------------- H(fp16) = (X * norm_src) @ W   (64x64 tile, 4x4/thread) ----
#define XS_STRIDE 68
__global__ __launch_bounds__(256)
void k_gemm64(const float* __restrict__ X, const float* __restrict__ norm,
              const float* __restrict__ W, __half* __restrict__ H, int N) {
    __shared__ float Xs[64 * XS_STRIDE];
    __shared__ float Ws[64 * 64];
    int tid = threadIdx.x;
    int rowBase = blockIdx.x * 64;

    for (int i = tid; i < 4096; i += 256) Ws[i] = W[i];
    for (int i = tid; i < 1024; i += 256) {
        int r  = i >> 4;
        int k4 = i & 15;
        int row = rowBase + r;
        float4 v = make_float4(0.f, 0.f, 0.f, 0.f);
        if (row < N) {
            v = ((const float4*)X)[(size_t)row * 16 + k4];
            float nv = norm[row];
            v.x *= nv; v.y *= nv; v.z *= nv; v.w *= nv;
        }
        *((float4*)&Xs[r * XS_STRIDE + (k4 << 2)]) = v;
    }
    __syncthreads();

    int tc = tid & 15;
    int tr = tid >> 4;
    int c0 = tc * 4, r0 = tr * 4;
    float acc[4][4] = {};

#pragma unroll
    for (int k = 0; k < 64; k += 4) {
        float4 xv[4];
#pragma unroll
        for (int j = 0; j < 4; j++)
            xv[j] = *((const float4*)&Xs[(r0 + j) * XS_STRIDE + k]);
#pragma unroll
        for (int kk = 0; kk < 4; kk++) {
            float4 wv = *((const float4*)&Ws[(k + kk) * 64 + c0]);
#pragma unroll
            for (int j = 0; j < 4; j++) {
                float xj = (kk == 0) ? xv[j].x : (kk == 1) ? xv[j].y
                         : (kk == 2) ? xv[j].z : xv[j].w;
                acc[j][0] += xj * wv.x;
                acc[j][1] += xj * wv.y;
                acc[j][2] += xj * wv.z;
                acc[j][3] += xj * wv.w;
            }
        }
    }
#pragma unroll
    for (int j = 0; j < 4; j++) {
        int row = rowBase + r0 + j;
        if (row < N) {
            __half2 h01 = __floats2half2_rn(acc[j][0], acc[j][1]);
            __half2 h23 = __floats2half2_rn(acc[j][2], acc[j][3]);
            uint2 pk;
            pk.x = *(unsigned int*)&h01;
            pk.y = *(unsigned int*)&h23;
            *((uint2*)(H + (size_t)row * 64 + c0)) = pk;
        }
    }
}

// ------- Out[i,:] = tanh( norm_dst[i] * sum_{e in row i} H[col[e], :] + b )
// one wave per node. 64 edge indices preloaded per wave (coalesced), shfl-
// distributed. fp16 rows: 128B each; lane group g (of 4) loads edge j+g as
// 8B/lane * 16 lanes = one full row per group -> 4 edges per vmem instr.
__global__ __launch_bounds__(256)
void k_agg(const uint2* __restrict__ H2, const int* __restrict__ rp,
           const int* __restrict__ deg, const int* __restrict__ col,
           const float* __restrict__ nd, const float4* __restrict__ bias4,
           float4* __restrict__ Out4, int N) {
    int wave = threadIdx.x >> 6;
    int lane = threadIdx.x & 63;
    int node = blockIdx.x * 4 + wave;
    if (node >= N) return;
    int start = rp[node];
    int n = deg[node];
    int g = lane >> 4;   // edge subgroup 0..3
    int l = lane & 15;   // uint2 (4-channel) index within row
    float ax = 0.f, ay = 0.f, az = 0.f, aw = 0.f;

    auto accum = [&](uint2 v) {
        float2 f01 = __half22float2(*(__half2*)&v.x);
        float2 f23 = __half22float2(*(__half2*)&v.y);
        ax += f01.x; ay += f01.y; az += f23.x; aw += f23.y;
    };

    for (int base = 0; base < n; base += 64) {
        int cnt = n - base;
        if (cnt > 64) cnt = 64;
        int idx = (lane < cnt) ? col[start + base + lane] : 0;
        int j = 0;
        for (; j + 16 <= cnt; j += 16) {
            int s0 = __shfl(idx, j + g);
            int s1 = __shfl(idx, j + 4 + g);
            int s2 = __shfl(idx, j + 8 + g);
            int s3 = __shfl(idx, j + 12 + g);
            uint2 v0 = H2[(size_t)s0 * 16 + l];
            uint2 v1 = H2[(size_t)s1 * 16 + l];
            uint2 v2 = H2[(size_t)s2 * 16 + l];
            uint2 v3 = H2[(size_t)s3 * 16 + l];
            accum(v0); accum(v1); accum(v2); accum(v3);
        }
        for (; j + 4 <= cnt; j += 4) {
            int s0 = __shfl(idx, j + g);
            uint2 v0 = H2[(size_t)s0 * 16 + l];
            accum(v0);
        }
        int t = cnt - j;
        if (t > 0) {
            int s0 = __shfl(idx, j + (g < t ? g : 0));
            if (g < t) {
                uint2 v0 = H2[(size_t)s0 * 16 + l];
                accum(v0);
            }
        }
    }
    // fold the 4 edge subgroups (xor 16, 32)
    ax += __shfl_xor(ax, 16); ay += __shfl_xor(ay, 16);
    az += __shfl_xor(az, 16); aw += __shfl_xor(aw, 16);
    ax += __shfl_xor(ax, 32); ay += __shfl_xor(ay, 32);
    az += __shfl_xor(az, 32); aw += __shfl_xor(aw, 32);

    if (lane < 16) {
        float nv = nd[node];
        float4 b = bias4[l];
        float4 r;
        r.x = tanhf(ax * nv + b.x);
        r.y = tanhf(ay * nv + b.y);
        r.z = tanhf(az * nv + b.z);
        r.w = tanhf(aw * nv + b.w);
        Out4[(size_t)node * 16 + l] = r;
    }
}

// ---------------- final FC: out = X @ Wfc + bfc  (64x10) ----------------
__global__ __launch_bounds__(640)
void k_fc(const float* __restrict__ X, const float* __restrict__ W,
          const float* __restrict__ b, float* __restrict__ out, int N) {
    __shared__ float Ws[640];
    __shared__ float bs[10];
    __shared__ float Xs[64 * 65];
    int tid = threadIdx.x;
    Ws[tid] = W[tid];
    if (tid < 10) bs[tid] = b[tid];
    int nodeBase = blockIdx.x * 64;
    for (int i = tid; i < 4096; i += 640) {
        int r = i >> 6, cc = i & 63;
        int nn = nodeBase + r;
        Xs[r * 65 + cc] = (nn < N) ? X[(size_t)nn * 64 + cc] : 0.0f;
    }
    __syncthreads();
    int ln = tid / 10, cl = tid % 10;
    float acc = bs[cl];
#pragma unroll
    for (int k = 0; k < 64; k++)
        acc += Xs[ln * 65 + k] * Ws[k * 10 + cl];
    int node = nodeBase + ln;
    if (node < N) out[(size_t)node * 10 + cl] = acc;
}

extern "C" void kernel_launch(void* const* d_in, const int* in_sizes, int n_in,
                              void* d_out, int out_size, void* d_ws, size_t ws_size,
                              hipStream_t stream) {
    const float* x   = (const float*)d_in[0];
    const int*   src = (const int*)d_in[1];
    const int*   dst = (const int*)d_in[2];
    const float* W1  = (const float*)d_in[3];
    const float* b1  = (const float*)d_in[4];
    const float* W2  = (const float*)d_in[5];
    const float* b2  = (const float*)d_in[6];
    const float* W3  = (const float*)d_in[7];
    const float* b3  = (const float*)d_in[8];
    const float* Wfc = (const float*)d_in[9];
    const float* bfc = (const float*)d_in[10];
    float* out = (float*)d_out;
    int N = in_sizes[0] / 64;
    int E = in_sizes[1];

    char* ws = (char*)d_ws;
    size_t p = 0;
    auto alloc = [&](size_t bytes) -> void* {
        void* r = ws + p;
        p = (p + bytes + 255) & ~(size_t)255;
        return r;
    };
    int*    deg_s = (int*)alloc((size_t)N * 4);
    int*    deg_d = (int*)alloc((size_t)N * 4);
    int*    rp    = (int*)alloc((size_t)N * 4);
    int*    bsum  = (int*)alloc((size_t)THREADS * 4);
    int*    rank  = (int*)alloc((size_t)E * 4);
    int*    col   = (int*)alloc((size_t)E * 4);
    float*  ns    = (float*)alloc((size_t)N * 4);
    float*  nd    = (float*)alloc((size_t)N * 4);
    __half* bufH  = (__half*)alloc((size_t)N * 64 * 2);
    float*  bufX  = (float*)alloc((size_t)N * 64 * 4);
    (void)ws_size; (void)n_in; (void)out_size;

    hipMemsetAsync(deg_s, 0, (size_t)N * 4, stream);
    hipMemsetAsync(deg_d, 0, (size_t)N * 4, stream);

    int gE = (E + THREADS - 1) / THREADS;
    int gN = (N + THREADS - 1) / THREADS;

    k_deg  <<<gE, THREADS, 0, stream>>>(src, dst, deg_s, deg_d, rank, E);
    k_scan1<<<gN, THREADS, 0, stream>>>(deg_d, rp, bsum, N);
    k_scan2<<<1,  THREADS, 0, stream>>>(bsum, gN);
    k_scan3<<<gN, THREADS, 0, stream>>>(rp, bsum, deg_s, deg_d, ns, nd, N);
    k_fill <<<gE, THREADS, 0, stream>>>(src, dst, rp, rank, col, E);

    int gG = (N + 63) / 64;
    int gA = (N + 3) / 4;
    int gF = (N + 63) / 64;

    k_gemm64<<<gG, 256, 0, stream>>>(x,    ns, W1, bufH, N);
    k_agg   <<<gA, 256, 0, stream>>>((const uint2*)bufH, rp, deg_d, col, nd,
                                     (const float4*)b1, (float4*)bufX, N);
    k_gemm64<<<gG, 256, 0, stream>>>(bufX, ns, W2, bufH, N);
    k_agg   <<<gA, 256, 0, stream>>>((const uint2*)bufH, rp, deg_d, col, nd,
                                     (const float4*)b2, (float4*)bufX, N);
    k_gemm64<<<gG, 256, 0, stream>>>(bufX, ns, W3, bufH, N);
    k_agg   <<<gA, 256, 0, stream>>>((const uint2*)bufH, rp, deg_d, col, nd,
                                     (const float4*)b3, (float4*)bufX, N);
    k_fc    <<<gF, 640, 0, stream>>>(bufX, Wfc, bfc, out, N);
}

// Round 4
// 304.201 us; speedup vs baseline: 1.3794x; 1.1414x over previous
//
#include <hip/hip_runtime.h>
#include <hip/hip_fp16.h>
#include <math.h>

#define THREADS 256
#define CHUNK_SHIFT 15
#define CHUNK (1 << CHUNK_SHIFT)
#define LDS_WORDS 25024   // >= ceil(N/2) for N=50000

// ---- privatized LDS histogram; dir 0 (dst) also captures local rank ----
__global__ __launch_bounds__(1024)
void k_hist(const int* __restrict__ src, const int* __restrict__ dst,
            unsigned int* __restrict__ partS, unsigned int* __restrict__ partD,
            int* __restrict__ rank, int E, int P, int words) {
    __shared__ unsigned int hist[LDS_WORDS];
    int isSrc = (blockIdx.x >= (unsigned)P);
    int b = isSrc ? (blockIdx.x - P) : blockIdx.x;
    int tid = threadIdx.x;

    for (int w = tid; w < words; w += 1024) hist[w] = 0u;
    __syncthreads();

    int start = b << CHUNK_SHIFT;
    int end = start + CHUNK; if (end > E) end = E;

    if (isSrc) {
        for (int e = start + tid; e < end; e += 1024) {
            int s = src[e];
            atomicAdd(&hist[s >> 1], 1u << ((s & 1) * 16));
        }
    } else {
        for (int e = start + tid; e < end; e += 1024) {
            int d = dst[e];
            unsigned int old = atomicAdd(&hist[d >> 1], 1u << ((d & 1) * 16));
            rank[e] = (int)((old >> ((d & 1) * 16)) & 0xFFFFu);
        }
    }
    __syncthreads();

    unsigned int* part = isSrc ? partS : partD;
    for (int w = tid; w < words; w += 1024)
        part[(size_t)b * words + w] = hist[w];
}

// ---- reduce partials -> deg arrays + norms; write back per-block prefixes --
__global__ void k_reduce(unsigned int* __restrict__ partS,
                         unsigned int* __restrict__ partD,
                         int* __restrict__ deg_s, int* __restrict__ deg_d,
                         float* __restrict__ ns, float* __restrict__ nd,
                         int P, int words, int N) {
    int w = blockIdx.x * blockDim.x + threadIdx.x;
    if (w >= words) return;
    unsigned int lo = 0, hi = 0;
    for (int b = 0; b < P; b++) {
        size_t off = (size_t)b * words + w;
        unsigned int v = partD[off];
        partD[off] = (hi << 16) | lo;          // exclusive across-block prefix
        lo += v & 0xFFFFu;
        hi += v >> 16;
    }
    unsigned int lo2 = 0, hi2 = 0;
    for (int b = 0; b < P; b++) {
        unsigned int v = partS[(size_t)b * words + w];
        lo2 += v & 0xFFFFu;
        hi2 += v >> 16;
    }
    int i0 = 2 * w, i1 = 2 * w + 1;
    deg_d[i0] = (int)lo;
    deg_s[i0] = (int)lo2;
    nd[i0] = lo  ? 1.0f / sqrtf((float)lo)  : 0.0f;
    ns[i0] = lo2 ? 1.0f / sqrtf((float)lo2) : 0.0f;
    if (i1 < N) {
        deg_d[i1] = (int)hi;
        deg_s[i1] = (int)hi2;
        nd[i1] = hi  ? 1.0f / sqrtf((float)hi)  : 0.0f;
        ns[i1] = hi2 ? 1.0f / sqrtf((float)hi2) : 0.0f;
    }
}

// ---------------- 3-kernel exclusive scan of deg_dst -> row_ptr ----------------
__global__ void k_scan1(const int* __restrict__ deg, int* __restrict__ excl,
                        int* __restrict__ bsum, int N) {
    __shared__ int s[THREADS];
    int t = threadIdx.x;
    int i = blockIdx.x * THREADS + t;
    int v = (i < N) ? deg[i] : 0;
    s[t] = v;
    __syncthreads();
    for (int off = 1; off < THREADS; off <<= 1) {
        int x = (t >= off) ? s[t - off] : 0;
        __syncthreads();
        s[t] += x;
        __syncthreads();
    }
    if (i < N) excl[i] = s[t] - v;
    if (t == THREADS - 1) bsum[blockIdx.x] = s[t];
}

__global__ void k_scan2(int* __restrict__ bsum, int nb) {
    __shared__ int s[THREADS];
    int t = threadIdx.x;
    int v = (t < nb) ? bsum[t] : 0;
    s[t] = v;
    __syncthreads();
    for (int off = 1; off < THREADS; off <<= 1) {
        int x = (t >= off) ? s[t - off] : 0;
        __syncthreads();
        s[t] += x;
        __syncthreads();
    }
    if (t < nb) bsum[t] = s[t] - v;
}

__global__ void k_scan3(int* __restrict__ rp, const int* __restrict__ bsum, int N) {
    int i = blockIdx.x * blockDim.x + threadIdx.x;
    if (i < N) rp[i] += bsum[i / THREADS];
}

// ---- CSR fill, atomic-free: rp + across-block prefix + local rank ----
__global__ void k_fill(const int* __restrict__ src, const int* __restrict__ dst,
                       const int* __restrict__ rp, const int* __restrict__ rank,
                       const unsigned int* __restrict__ partD,
                       int* __restrict__ col, int E, int words) {
    int e = blockIdx.x * blockDim.x + threadIdx.x;
    if (e < E) {
        int d = dst[e];
        int b = e >> CHUNK_SHIFT;
        unsigned int pk = partD[(size_t)b * words + (d >> 1)];
        int pref = (int)((pk >> ((d & 1) * 16)) & 0xFFFFu);
        col[rp[d] + pref + rank[e]] = src[e];
    }
}

// ---------------- H(fp16) = (X * norm_src) @ W   (64x64 tile, 4x4/thread) ----
#define XS_STRIDE 68
__global__ __launch_bounds__(256)
void k_gemm64(const float* __restrict__ X, const float* __restrict__ norm,
              const float* __restrict__ W, __half* __restrict__ H, int N) {
    __shared__ float Xs[64 * XS_STRIDE];
    __shared__ float Ws[64 * 64];
    int tid = threadIdx.x;
    int rowBase = blockIdx.x * 64;

    for (int i = tid; i < 4096; i += 256) Ws[i] = W[i];
    for (int i = tid; i < 1024; i += 256) {
        int r  = i >> 4;
        int k4 = i & 15;
        int row = rowBase + r;
        float4 v = make_float4(0.f, 0.f, 0.f, 0.f);
        if (row < N) {
            v = ((const float4*)X)[(size_t)row * 16 + k4];
            float nv = norm[row];
            v.x *= nv; v.y *= nv; v.z *= nv; v.w *= nv;
        }
        *((float4*)&Xs[r * XS_STRIDE + (k4 << 2)]) = v;
    }
    __syncthreads();

    int tc = tid & 15;
    int tr = tid >> 4;
    int c0 = tc * 4, r0 = tr * 4;
    float acc[4][4] = {};

#pragma unroll
    for (int k = 0; k < 64; k += 4) {
        float4 xv[4];
#pragma unroll
        for (int j = 0; j < 4; j++)
            xv[j] = *((const float4*)&Xs[(r0 + j) * XS_STRIDE + k]);
#pragma unroll
        for (int kk = 0; kk < 4; kk++) {
            float4 wv = *((const float4*)&Ws[(k + kk) * 64 + c0]);
#pragma unroll
            for (int j = 0; j < 4; j++) {
                float xj = (kk == 0) ? xv[j].x : (kk == 1) ? xv[j].y
                         : (kk == 2) ? xv[j].z : xv[j].w;
                acc[j][0] += xj * wv.x;
                acc[j][1] += xj * wv.y;
                acc[j][2] += xj * wv.z;
                acc[j][3] += xj * wv.w;
            }
        }
    }
#pragma unroll
    for (int j = 0; j < 4; j++) {
        int row = rowBase + r0 + j;
        if (row < N) {
            __half2 h01 = __floats2half2_rn(acc[j][0], acc[j][1]);
            __half2 h23 = __floats2half2_rn(acc[j][2], acc[j][3]);
            uint2 pk;
            pk.x = *(unsigned int*)&h01;
            pk.y = *(unsigned int*)&h23;
            *((uint2*)(H + (size_t)row * 64 + c0)) = pk;
        }
    }
}

// ------- Out[i,:] = tanh( norm_dst[i] * sum_{e in row i} H[col[e], :] + b )
__global__ __launch_bounds__(256)
void k_agg(const uint2* __restrict__ H2, const int* __restrict__ rp,
           const int* __restrict__ deg, const int* __restrict__ col,
           const float* __restrict__ nd, const float4* __restrict__ bias4,
           float4* __restrict__ Out4, int N) {
    int wave = threadIdx.x >> 6;
    int lane = threadIdx.x & 63;
    int node = blockIdx.x * 4 + wave;
    if (node >= N) return;
    int start = rp[node];
    int n = deg[node];
    int g = lane >> 4;
    int l = lane & 15;
    float ax = 0.f, ay = 0.f, az = 0.f, aw = 0.f;

    auto accum = [&](uint2 v) {
        float2 f01 = __half22float2(*(__half2*)&v.x);
        float2 f23 = __half22float2(*(__half2*)&v.y);
        ax += f01.x; ay += f01.y; az += f23.x; aw += f23.y;
    };

    for (int base = 0; base < n; base += 64) {
        int cnt = n - base;
        if (cnt > 64) cnt = 64;
        int idx = (lane < cnt) ? col[start + base + lane] : 0;
        int j = 0;
        for (; j + 16 <= cnt; j += 16) {
            int s0 = __shfl(idx, j + g);
            int s1 = __shfl(idx, j + 4 + g);
            int s2 = __shfl(idx, j + 8 + g);
            int s3 = __shfl(idx, j + 12 + g);
            uint2 v0 = H2[(size_t)s0 * 16 + l];
            uint2 v1 = H2[(size_t)s1 * 16 + l];
            uint2 v2 = H2[(size_t)s2 * 16 + l];
            uint2 v3 = H2[(size_t)s3 * 16 + l];
            accum(v0); accum(v1); accum(v2); accum(v3);
        }
        for (; j + 4 <= cnt; j += 4) {
            int s0 = __shfl(idx, j + g);
            uint2 v0 = H2[(size_t)s0 * 16 + l];
            accum(v0);
        }
        int t = cnt - j;
        if (t > 0) {
            int s0 = __shfl(idx, j + (g < t ? g : 0));
            if (g < t) {
                uint2 v0 = H2[(size_t)s0 * 16 + l];
                accum(v0);
            }
        }
    }
    ax += __shfl_xor(ax, 16); ay += __shfl_xor(ay, 16);
    az += __shfl_xor(az, 16); aw += __shfl_xor(aw, 16);
    ax += __shfl_xor(ax, 32); ay += __shfl_xor(ay, 32);
    az += __shfl_xor(az, 32); aw += __shfl_xor(aw, 32);

    if (lane < 16) {
        float nv = nd[node];
        float4 b = bias4[l];
        float4 r;
        r.x = tanhf(ax * nv + b.x);
        r.y = tanhf(ay * nv + b.y);
        r.z = tanhf(az * nv + b.z);
        r.w = tanhf(aw * nv + b.w);
        Out4[(size_t)node * 16 + l] = r;
    }
}

// ---------------- final FC: out = X @ Wfc + bfc  (64x10) ----------------
__global__ __launch_bounds__(640)
void k_fc(const float* __restrict__ X, const float* __restrict__ W,
          const float* __restrict__ b, float* __restrict__ out, int N) {
    __shared__ float Ws[640];
    __shared__ float bs[10];
    __shared__ float Xs[64 * 65];
    int tid = threadIdx.x;
    Ws[tid] = W[tid];
    if (tid < 10) bs[tid] = b[tid];
    int nodeBase = blockIdx.x * 64;
    for (int i = tid; i < 4096; i += 640) {
        int r = i >> 6, cc = i & 63;
        int nn = nodeBase + r;
        Xs[r * 65 + cc] = (nn < N) ? X[(size_t)nn * 64 + cc] : 0.0f;
    }
    __syncthreads();
    int ln = tid / 10, cl = tid % 10;
    float acc = bs[cl];
#pragma unroll
    for (int k = 0; k < 64; k++)
        acc += Xs[ln * 65 + k] * Ws[k * 10 + cl];
    int node = nodeBase + ln;
    if (node < N) out[(size_t)node * 10 + cl] = acc;
}

extern "C" void kernel_launch(void* const* d_in, const int* in_sizes, int n_in,
                              void* d_out, int out_size, void* d_ws, size_t ws_size,
                              hipStream_t stream) {
    const float* x   = (const float*)d_in[0];
    const int*   src = (const int*)d_in[1];
    const int*   dst = (const int*)d_in[2];
    const float* W1  = (const float*)d_in[3];
    const float* b1  = (const float*)d_in[4];
    const float* W2  = (const float*)d_in[5];
    const float* b2  = (const float*)d_in[6];
    const float* W3  = (const float*)d_in[7];
    const float* b3  = (const float*)d_in[8];
    const float* Wfc = (const float*)d_in[9];
    const float* bfc = (const float*)d_in[10];
    float* out = (float*)d_out;
    int N = in_sizes[0] / 64;
    int E = in_sizes[1];
    int P = (E + CHUNK - 1) >> CHUNK_SHIFT;   // hist blocks per direction
    int words = (N + 1) / 2;                  // packed 2 bins per u32

    char* ws = (char*)d_ws;
    size_t p = 0;
    auto alloc = [&](size_t bytes) -> void* {
        void* r = ws + p;
        p = (p + bytes + 255) & ~(size_t)255;
        return r;
    };
    int*    deg_s = (int*)alloc((size_t)N * 4);
    int*    deg_d = (int*)alloc((size_t)N * 4);
    int*    rp    = (int*)alloc((size_t)N * 4);
    int*    bsum  = (int*)alloc((size_t)THREADS * 4);
    int*    rank  = (int*)alloc((size_t)E * 4);
    int*    col   = (int*)alloc((size_t)E * 4);
    float*  ns    = (float*)alloc((size_t)N * 4);
    float*  nd    = (float*)alloc((size_t)N * 4);
    unsigned int* partS = (unsigned int*)alloc((size_t)P * words * 4);
    unsigned int* partD = (unsigned int*)alloc((size_t)P * words * 4);
    __half* bufH  = (__half*)alloc((size_t)N * 64 * 2);
    float*  bufX  = (float*)alloc((size_t)N * 64 * 4);
    (void)ws_size; (void)n_in; (void)out_size;

    int gE = (E + THREADS - 1) / THREADS;
    int gN = (N + THREADS - 1) / THREADS;
    int gW = (words + THREADS - 1) / THREADS;

    k_hist  <<<2 * P, 1024, 0, stream>>>(src, dst, partS, partD, rank, E, P, words);
    k_reduce<<<gW, THREADS, 0, stream>>>(partS, partD, deg_s, deg_d, ns, nd, P, words, N);
    k_scan1 <<<gN, THREADS, 0, stream>>>(deg_d, rp, bsum, N);
    k_scan2 <<<1,  THREADS, 0, stream>>>(bsum, gN);
    k_scan3 <<<gN, THREADS, 0, stream>>>(rp, bsum, N);
    k_fill  <<<gE, THREADS, 0, stream>>>(src, dst, rp, rank, partD, col, E, words);

    int gG = (N + 63) / 64;
    int gA = (N + 3) / 4;
    int gF = (N + 63) / 64;

    k_gemm64<<<gG, 256, 0, stream>>>(x,    ns, W1, bufH, N);
    k_agg   <<<gA, 256, 0, stream>>>((const uint2*)bufH, rp, deg_d, col, nd,
                                     (const float4*)b1, (float4*)bufX, N);
    k_gemm64<<<gG, 256, 0, stream>>>(bufX, ns, W2, bufH, N);
    k_agg   <<<gA, 256, 0, stream>>>((const uint2*)bufH, rp, deg_d, col, nd,
                                     (const float4*)b2, (float4*)bufX, N);
    k_gemm64<<<gG, 256, 0, stream>>>(bufX, ns, W3, bufH, N);
    k_agg   <<<gA, 256, 0, stream>>>((const uint2*)bufH, rp, deg_d, col, nd,
                                     (const float4*)b3, (float4*)bufX, N);
    k_fc    <<<gF, 640, 0, stream>>>(bufX, Wfc, bfc, out, N);
}